// Round 1
// baseline (359.382 us; speedup 1.0000x reference)
//
#include <hip/hip_runtime.h>

// WeightedSumSessEmbedding: out[s, :] = sum_{j: row_idx[j]==s} data[j] * emb[col_idx[j], :]
// row_idx sorted -> per-session contiguous segment; binary search bounds,
// register-accumulate, no atomics. EMB_DIM = 64 floats = 16 float4.
//
// Wave layout: 64 lanes = 4 groups (r = lane>>4) x 16 lanes (c = lane&15).
// Group r handles nnz j0+r; lane c loads float4 #c of that row (16B/lane,
// 1KB per wave-instruction). Cross-group reduce via shfl_xor(16),(32).

__global__ __launch_bounds__(256) void wsum_sess_kernel(
    const int*    __restrict__ row_idx,
    const int*    __restrict__ col_idx,
    const float*  __restrict__ data,
    const float4* __restrict__ emb,   // [ITEMS_NUM, 16] as float4
    float4*       __restrict__ out,   // [num_sess, 16] as float4
    int nnz, int num_sess)
{
    const int wave = threadIdx.x >> 6;           // 0..3
    const int lane = threadIdx.x & 63;
    const int sess = (blockIdx.x << 2) + wave;   // one wave per session
    if (sess >= num_sess) return;

    // lower_bound(row_idx, sess) and lower_bound(row_idx, sess+1)
    // (uniform across the wave; ~20 broadcast loads each)
    int lo = 0, hi = nnz;
    while (lo < hi) {
        int mid = (lo + hi) >> 1;
        if (row_idx[mid] < sess) lo = mid + 1; else hi = mid;
    }
    const int start = lo;
    hi = nnz;
    while (lo < hi) {
        int mid = (lo + hi) >> 1;
        if (row_idx[mid] < sess + 1) lo = mid + 1; else hi = mid;
    }
    const int end = lo;

    const int r = lane >> 4;   // which of 4 nnz in this group-of-4
    const int c = lane & 15;   // float4 slot within the 64-float row

    float4 acc = make_float4(0.f, 0.f, 0.f, 0.f);

    // 8 nnz per iteration (2 independent gathers in flight per lane)
    int j0 = start;
    for (; j0 + 8 <= end; j0 += 8) {
        int   ja = j0 + r;
        int   jb = j0 + 4 + r;
        int   ca = col_idx[ja];
        int   cb = col_idx[jb];
        float wa = data[ja];
        float wb = data[jb];
        float4 ea = emb[(size_t)ca * 16 + c];
        float4 eb = emb[(size_t)cb * 16 + c];
        acc.x += wa * ea.x + wb * eb.x;
        acc.y += wa * ea.y + wb * eb.y;
        acc.z += wa * ea.z + wb * eb.z;
        acc.w += wa * ea.w + wb * eb.w;
    }
    // tail: up to 7 nnz, 4 at a time with masking
    for (; j0 < end; j0 += 4) {
        int   j     = j0 + r;
        bool  valid = (j < end);
        int   col   = valid ? col_idx[j] : 0;
        float w     = valid ? data[j]    : 0.f;
        float4 e = emb[(size_t)col * 16 + c];
        acc.x += w * e.x;
        acc.y += w * e.y;
        acc.z += w * e.z;
        acc.w += w * e.w;
    }

    // reduce the 4 lane-groups (lanes differing in bits 4,5 hold same dims)
    acc.x += __shfl_xor(acc.x, 16, 64);
    acc.y += __shfl_xor(acc.y, 16, 64);
    acc.z += __shfl_xor(acc.z, 16, 64);
    acc.w += __shfl_xor(acc.w, 16, 64);
    acc.x += __shfl_xor(acc.x, 32, 64);
    acc.y += __shfl_xor(acc.y, 32, 64);
    acc.z += __shfl_xor(acc.z, 32, 64);
    acc.w += __shfl_xor(acc.w, 32, 64);

    if (r == 0)
        out[(size_t)sess * 16 + c] = acc;
}

extern "C" void kernel_launch(void* const* d_in, const int* in_sizes, int n_in,
                              void* d_out, int out_size, void* d_ws, size_t ws_size,
                              hipStream_t stream) {
    const int*   row_idx = (const int*)  d_in[0];
    const int*   col_idx = (const int*)  d_in[1];
    const float* data    = (const float*)d_in[2];
    // d_in[3] = num_ids scalar on device; derive from out_size instead
    const float* emb     = (const float*)d_in[4];

    const int nnz      = in_sizes[0];
    const int num_sess = out_size / 64;   // EMB_DIM = 64

    const int blocks = (num_sess + 3) / 4;   // 4 waves/block, 1 session/wave
    wsum_sess_kernel<<<blocks, 256, 0, stream>>>(
        row_idx, col_idx, data, (const float4*)emb, (float4*)d_out,
        nnz, num_sess);
}

// Round 2
// 325.287 us; speedup vs baseline: 1.1048x; 1.1048x over previous
//
#include <hip/hip_runtime.h>

// WeightedSumSessEmbedding: out[s,:] = sum_{j: row_idx[j]==s} data[j] * emb[col_idx[j],:]
// row_idx sorted. Two kernels:
//   1) build_rowptr: CSR-style row_ptr[num_sess+1] in d_ws (boundary detect,
//      each entry written exactly once -> deterministic, no init needed).
//   2) wsum: one wave per session; 64 lanes = 4 nnz-groups x 16 float4-lanes
//      (16B/lane, 256B/row). 16 nnz per iter -> 4 independent col->emb gather
//      chains in flight. Cross-group reduce via shfl_xor(16),(32).
// No atomics, out written exactly once -> no zero-init of d_out.

__global__ __launch_bounds__(256) void build_rowptr_kernel(
    const int* __restrict__ row_idx,
    int*       __restrict__ row_ptr,   // [num_sess+1]
    int nnz, int num_sess)
{
    int j = blockIdx.x * blockDim.x + threadIdx.x;
    if (j >= nnz) return;
    int r = row_idx[j];
    if (j == 0) {
        for (int s = 0; s <= r; ++s) row_ptr[s] = 0;        // lower_bound(s)=0 for s<=row[0]
    } else {
        int rp = row_idx[j - 1];
        for (int s = rp + 1; s <= r; ++s) row_ptr[s] = j;   // first idx >= s is j
    }
    if (j == nnz - 1) {
        for (int s = r + 1; s <= num_sess; ++s) row_ptr[s] = nnz;
    }
}

__global__ __launch_bounds__(256, 8) void wsum_sess_kernel(
    const int*    __restrict__ row_ptr,
    const int*    __restrict__ col_idx,
    const float*  __restrict__ data,
    const float4* __restrict__ emb,   // [ITEMS_NUM, 16] as float4
    float4*       __restrict__ out,   // [num_sess, 16] as float4
    int num_sess)
{
    const int wave = threadIdx.x >> 6;           // 0..3
    const int lane = threadIdx.x & 63;
    const int sess = (blockIdx.x << 2) + wave;   // one wave per session
    if (sess >= num_sess) return;

    const int start = row_ptr[sess];
    const int end   = row_ptr[sess + 1];

    const int r = lane >> 4;   // nnz slot within group-of-4
    const int c = lane & 15;   // float4 slot within the 64-float row

    float4 acc = make_float4(0.f, 0.f, 0.f, 0.f);

    int j0 = start;
    // 16 nnz per iteration: 4 independent gather chains in flight per lane
    for (; j0 + 16 <= end; j0 += 16) {
        int   c0 = col_idx[j0 + 0  + r];
        int   c1 = col_idx[j0 + 4  + r];
        int   c2 = col_idx[j0 + 8  + r];
        int   c3 = col_idx[j0 + 12 + r];
        float w0 = data[j0 + 0  + r];
        float w1 = data[j0 + 4  + r];
        float w2 = data[j0 + 8  + r];
        float w3 = data[j0 + 12 + r];
        float4 e0 = emb[((size_t)c0 << 4) + c];
        float4 e1 = emb[((size_t)c1 << 4) + c];
        float4 e2 = emb[((size_t)c2 << 4) + c];
        float4 e3 = emb[((size_t)c3 << 4) + c];
        acc.x += w0 * e0.x + w1 * e1.x + w2 * e2.x + w3 * e3.x;
        acc.y += w0 * e0.y + w1 * e1.y + w2 * e2.y + w3 * e3.y;
        acc.z += w0 * e0.z + w1 * e1.z + w2 * e2.z + w3 * e3.z;
        acc.w += w0 * e0.w + w1 * e1.w + w2 * e2.w + w3 * e3.w;
    }
    // tail: 4 nnz at a time with masking (up to 4 passes)
    for (; j0 < end; j0 += 4) {
        int   j     = j0 + r;
        bool  valid = (j < end);
        int   col   = valid ? col_idx[j] : 0;
        float w     = valid ? data[j]    : 0.f;
        float4 e = emb[((size_t)col << 4) + c];
        acc.x += w * e.x;
        acc.y += w * e.y;
        acc.z += w * e.z;
        acc.w += w * e.w;
    }

    // reduce the 4 lane-groups (lanes differing in bits 4,5 hold same dims)
    acc.x += __shfl_xor(acc.x, 16, 64);
    acc.y += __shfl_xor(acc.y, 16, 64);
    acc.z += __shfl_xor(acc.z, 16, 64);
    acc.w += __shfl_xor(acc.w, 16, 64);
    acc.x += __shfl_xor(acc.x, 32, 64);
    acc.y += __shfl_xor(acc.y, 32, 64);
    acc.z += __shfl_xor(acc.z, 32, 64);
    acc.w += __shfl_xor(acc.w, 32, 64);

    if (r == 0)
        out[((size_t)sess << 4) + c] = acc;
}

extern "C" void kernel_launch(void* const* d_in, const int* in_sizes, int n_in,
                              void* d_out, int out_size, void* d_ws, size_t ws_size,
                              hipStream_t stream) {
    const int*   row_idx = (const int*)  d_in[0];
    const int*   col_idx = (const int*)  d_in[1];
    const float* data    = (const float*)d_in[2];
    const float* emb     = (const float*)d_in[4];

    const int nnz      = in_sizes[0];
    const int num_sess = out_size / 64;   // EMB_DIM = 64

    int* row_ptr = (int*)d_ws;            // num_sess+1 ints (< 64KB+4)

    build_rowptr_kernel<<<(nnz + 255) / 256, 256, 0, stream>>>(
        row_idx, row_ptr, nnz, num_sess);

    const int blocks = (num_sess + 3) / 4;   // 4 waves/block, 1 session/wave
    wsum_sess_kernel<<<blocks, 256, 0, stream>>>(
        row_ptr, col_idx, data, (const float4*)emb, (float4*)d_out,
        num_sess);
}